// Round 1
// baseline (458.171 us; speedup 1.0000x reference)
//
#include <hip/hip_runtime.h>
#include <hip/hip_fp16.h>

// B=8, N=1024, E=512, H=8, D=64
// ws layout (f16): QB[64][1024][64], K[64][1024][64], VT[64][64][1024],
//                  WRS[64][1024][64], OUT1[8192][512], BD[64][1024][1024]
// total = 5*4194304 + 67108864 f16 = 176,160,768 bytes

typedef _Float16 f16;
typedef f16 f16x4 __attribute__((ext_vector_type(4)));
typedef f16 f16x8 __attribute__((ext_vector_type(8)));
typedef float f32x4 __attribute__((ext_vector_type(4)));

#define MFMA16(a,b,c) __builtin_amdgcn_mfma_f32_16x16x32_f16((a),(b),(c),0,0,0)

static __device__ __forceinline__ f16x8 cat8(f16x4 lo, f16x4 hi) {
  return __builtin_shufflevector(lo, hi, 0, 1, 2, 3, 4, 5, 6, 7);
}

// ---------------- Kernel A: projections ----------------
// grid (64, 32): x=mtile(128 rows), y=ntile(64 cols of virtual 2048)
// cols 0-511: Q(+bias)->QB[b,h,n,d]; 512-1023: K->K[b,h,n,d];
// 1024-1535: V->VT[b,h,d,n]; 1536-2047: WRS = rt@wkrt + rc@wkrc ->[b,h,n,d]
__global__ __launch_bounds__(256) void kproj(
    const float* __restrict__ x, const float* __restrict__ rt, const float* __restrict__ rc,
    const float* __restrict__ wqkv, const float* __restrict__ wkrt, const float* __restrict__ wkrc,
    const float* __restrict__ bias_te,
    f16* __restrict__ QB, f16* __restrict__ Kf, f16* __restrict__ VT, f16* __restrict__ WRS)
{
  __shared__ f16 a_s[128][36];
  __shared__ f16 b_s[64][36];
  const int t = threadIdx.x, l = t & 63, w = t >> 6;
  const int m0 = blockIdx.x * 128;
  const int c0 = blockIdx.y * 64;
  const int mode = c0 >> 9;  // 0:Q 1:K 2:V 3:WRS
  f32x4 acc[2][4] = {};
  const int nsrc = (mode == 3) ? 2 : 1;
  for (int src = 0; src < nsrc; ++src) {
    const float* Ap = (mode == 3) ? (src ? rc : rt) : x;
    const float* Bp = (mode == 3) ? (src ? wkrc : wkrt) : wqkv;
    const int bstride = (mode == 3) ? 512 : 1536;
    const int bc0 = (mode == 3) ? (c0 - 1536) : c0;
    for (int k0 = 0; k0 < 512; k0 += 32) {
      __syncthreads();
      #pragma unroll
      for (int rep = 0; rep < 4; ++rep) {          // A tile 128x32 fp32->f16
        int idx = rep * 1024 + t * 4;
        int r = idx >> 5, c = idx & 31;
        float4 v = *(const float4*)&Ap[(size_t)(m0 + r) * 512 + k0 + c];
        *(f16x4*)&a_s[r][c] = f16x4{(f16)v.x, (f16)v.y, (f16)v.z, (f16)v.w};
      }
      #pragma unroll
      for (int rep = 0; rep < 2; ++rep) {          // B tile 32x64 -> transposed [n][k]
        int idx = rep * 1024 + t * 4;
        int kr = idx >> 6, c = idx & 63;
        float4 v = *(const float4*)&Bp[(size_t)(k0 + kr) * bstride + bc0 + c];
        b_s[c + 0][kr] = (f16)v.x; b_s[c + 1][kr] = (f16)v.y;
        b_s[c + 2][kr] = (f16)v.z; b_s[c + 3][kr] = (f16)v.w;
      }
      __syncthreads();
      const int kc = (l >> 4) * 8;
      f16x8 af[2];
      #pragma unroll
      for (int mb = 0; mb < 2; ++mb) {
        int r = w * 32 + mb * 16 + (l & 15);
        af[mb] = cat8(*(const f16x4*)&a_s[r][kc], *(const f16x4*)&a_s[r][kc + 4]);
      }
      #pragma unroll
      for (int nb = 0; nb < 4; ++nb) {
        int cc = nb * 16 + (l & 15);
        f16x8 bf = cat8(*(const f16x4*)&b_s[cc][kc], *(const f16x4*)&b_s[cc][kc + 4]);
        #pragma unroll
        for (int mb = 0; mb < 2; ++mb)
          acc[mb][nb] = MFMA16(af[mb], bf, acc[mb][nb]);
      }
    }
  }
  // epilogue: C/D layout col=lane&15, row=(lane>>4)*4+reg
  #pragma unroll
  for (int mb = 0; mb < 2; ++mb)
  #pragma unroll
  for (int nb = 0; nb < 4; ++nb) {
    const int cg = c0 + nb * 16 + (l & 15);
    const int mbase = m0 + w * 32 + mb * 16 + (l >> 4) * 4;
    const int bb = mbase >> 10, nbase = mbase & 1023;
    if (mode == 2) {
      const int cv = cg - 1024, hh = cv >> 6, dd = cv & 63;
      f32x4 a = acc[mb][nb];
      *(f16x4*)&VT[(((size_t)bb * 8 + hh) * 64 + dd) * 1024 + nbase] =
          f16x4{(f16)a[0], (f16)a[1], (f16)a[2], (f16)a[3]};
    } else {
      f16* outp; int cl; float badd = 0.f;
      if (mode == 0) { outp = QB; cl = cg; badd = bias_te[cg]; }
      else if (mode == 1) { outp = Kf; cl = cg - 512; }
      else { outp = WRS; cl = cg - 1536; }
      const int hh = cl >> 6, dd = cl & 63;
      #pragma unroll
      for (int r = 0; r < 4; ++r)
        outp[(((size_t)bb * 8 + hh) * 1024 + (nbase + r)) * 64 + dd] =
            (f16)(acc[mb][nb][r] + badd);
    }
  }
}

// ---------------- Kernel B: rawsum GEMM + rel_shift scatter ----------------
// raw[i,j] = sum_d QB[i,d]*WRS[j,d]; dest: i+j>=N-1 ? (i, i+j-N+1) : (i-1, i+j+1)
// (q,q+1) slots are never written (the rel_shift zero) -> masked in kernel C.
__global__ __launch_bounds__(256) void krel(
    const f16* __restrict__ QB, const f16* __restrict__ WRS, f16* __restrict__ BD)
{
  const int t = threadIdx.x, l = t & 63, w = t >> 6;
  const int j0 = blockIdx.x * 64;
  const int i0 = blockIdx.y * 64;
  const int bh = blockIdx.z;
  const size_t base = (size_t)bh * 65536;  // 1024*64
  f32x4 acc[4] = {};
  const int i_f = i0 + w * 16 + (l & 15);
  #pragma unroll
  for (int kc = 0; kc < 2; ++kc) {
    const int dc = kc * 32 + (l >> 4) * 8;
    f16x8 af = *(const f16x8*)&QB[base + (size_t)i_f * 64 + dc];
    #pragma unroll
    for (int nb = 0; nb < 4; ++nb) {
      int j = j0 + nb * 16 + (l & 15);
      f16x8 bf = *(const f16x8*)&WRS[base + (size_t)j * 64 + dc];
      acc[nb] = MFMA16(af, bf, acc[nb]);
    }
  }
  const size_t bdb = (size_t)bh << 20;
  #pragma unroll
  for (int nb = 0; nb < 4; ++nb)
  #pragma unroll
  for (int r = 0; r < 4; ++r) {
    const int i = i0 + w * 16 + (l >> 4) * 4 + r;
    const int j = j0 + nb * 16 + (l & 15);
    const int s = i + j;
    int q, k;
    if (s >= 1023) { q = i; k = s - 1023; }
    else           { q = i - 1; k = s + 1; }
    if (q >= 0) BD[bdb + (size_t)q * 1024 + k] = (f16)acc[nb][r];
  }
}

// ---------------- Kernel C: AC + BD + h-softmax + attn out + PV ----------------
// grid 256 = b(8) x qtile(32 rows); 512 threads, wave = head.
__global__ __launch_bounds__(512) void kattn(
    const f16* __restrict__ QB, const f16* __restrict__ Kf, const f16* __restrict__ VT,
    const f16* __restrict__ BD, float* __restrict__ attn_out, f16* __restrict__ OUT1)
{
  __shared__ f16 sd[8][32][72];  // dots/attn, stride 72 (16B-aligned rows, low conflict)
  const int t = threadIdx.x, l = t & 63, h = t >> 6;
  const int b = blockIdx.x >> 5, qt = blockIdx.x & 31;
  const int q0 = qt * 32;
  const int bh = b * 8 + h;
  const size_t base = (size_t)bh * 65536;
  const size_t bdb = (size_t)bh << 20;
  // preload Q fragments (A-operand: row=l&15, k-elems contiguous 8 at (l>>4)*8)
  f16x8 aq[2][2];
  #pragma unroll
  for (int mb = 0; mb < 2; ++mb)
  #pragma unroll
  for (int kc = 0; kc < 2; ++kc) {
    int qg = q0 + mb * 16 + (l & 15);
    int dc = kc * 32 + (l >> 4) * 8;
    aq[mb][kc] = *(const f16x8*)&QB[base + (size_t)qg * 64 + dc];
  }
  f32x4 oacc[2][4] = {};
  for (int kt = 0; kt < 16; ++kt) {
    const int k0 = kt * 64;
    // ---- AC = QB . K^T ----
    f32x4 acc[2][4] = {};
    #pragma unroll
    for (int kc = 0; kc < 2; ++kc) {
      const int dc = kc * 32 + (l >> 4) * 8;
      #pragma unroll
      for (int nb = 0; nb < 4; ++nb) {
        int jg = k0 + nb * 16 + (l & 15);
        f16x8 bf = *(const f16x8*)&Kf[base + (size_t)jg * 64 + dc];
        #pragma unroll
        for (int mb = 0; mb < 2; ++mb)
          acc[mb][nb] = MFMA16(aq[mb][kc], bf, acc[mb][nb]);
      }
    }
    #pragma unroll
    for (int mb = 0; mb < 2; ++mb)
    #pragma unroll
    for (int nb = 0; nb < 4; ++nb)
    #pragma unroll
    for (int r = 0; r < 4; ++r)
      sd[h][mb * 16 + (l >> 4) * 4 + r][nb * 16 + (l & 15)] = (f16)acc[mb][nb][r];
    __syncthreads();
    // ---- dots += 0.5*BD (mask the k==q+1 rel-shift zero slot) ----
    #pragma unroll
    for (int s = 0; s < 4; ++s) {
      const int o = s * 512 + l * 8;
      const int q = o >> 6, k = o & 63;
      f16x8 bd = *(const f16x8*)&BD[bdb + (size_t)(q0 + q) * 1024 + k0 + k];
      f16x8 cur = *(f16x8*)&sd[h][q][k];
      const int qg1 = q0 + q + 1;
      #pragma unroll
      for (int e = 0; e < 8; ++e) {
        float vv = (float)cur[e];
        if (k0 + k + e != qg1) vv += 0.5f * (float)bd[e];
        cur[e] = (f16)vv;
      }
      *(f16x8*)&sd[h][q][k] = cur;
    }
    __syncthreads();
    // ---- softmax over heads + attn write ----
    {
      const int o = t * 4, q = o >> 6, k = o & 63;
      float dv[8][4];
      #pragma unroll
      for (int hh = 0; hh < 8; ++hh) {
        f16x4 v = *(const f16x4*)&sd[hh][q][k];
        dv[hh][0] = (float)v[0]; dv[hh][1] = (float)v[1];
        dv[hh][2] = (float)v[2]; dv[hh][3] = (float)v[3];
      }
      #pragma unroll
      for (int e = 0; e < 4; ++e) {
        float m = dv[0][e];
        #pragma unroll
        for (int hh = 1; hh < 8; ++hh) m = fmaxf(m, dv[hh][e]);
        float ssum = 0.f;
        #pragma unroll
        for (int hh = 0; hh < 8; ++hh) { float a = __expf(dv[hh][e] - m); dv[hh][e] = a; ssum += a; }
        float rinv = 1.f / ssum;
        #pragma unroll
        for (int hh = 0; hh < 8; ++hh) dv[hh][e] *= rinv;
      }
      const size_t qg = q0 + q;
      #pragma unroll
      for (int hh = 0; hh < 8; ++hh) {
        *(float4*)&attn_out[((size_t)(b * 8 + hh) * 1024 + qg) * 1024 + k0 + k] =
            float4{dv[hh][0], dv[hh][1], dv[hh][2], dv[hh][3]};
        *(f16x4*)&sd[hh][q][k] =
            f16x4{(f16)dv[hh][0], (f16)dv[hh][1], (f16)dv[hh][2], (f16)dv[hh][3]};
      }
    }
    __syncthreads();
    // ---- PV: oacc[q,d] += attn[q,j] * V[j,d]  (B from VT[b,h,d,n]) ----
    #pragma unroll
    for (int kc = 0; kc < 2; ++kc) {
      f16x8 pa[2];
      #pragma unroll
      for (int mb = 0; mb < 2; ++mb) {
        int qq = mb * 16 + (l & 15);
        int jj = kc * 32 + (l >> 4) * 8;
        pa[mb] = *(const f16x8*)&sd[h][qq][jj];
      }
      #pragma unroll
      for (int nb = 0; nb < 4; ++nb) {
        int dd = nb * 16 + (l & 15);
        int jg = k0 + kc * 32 + (l >> 4) * 8;
        f16x8 vb = *(const f16x8*)&VT[base + (size_t)dd * 1024 + jg];
        #pragma unroll
        for (int mb = 0; mb < 2; ++mb)
          oacc[mb][nb] = MFMA16(pa[mb], vb, oacc[mb][nb]);
      }
    }
    __syncthreads();
  }
  #pragma unroll
  for (int mb = 0; mb < 2; ++mb)
  #pragma unroll
  for (int nb = 0; nb < 4; ++nb)
  #pragma unroll
  for (int r = 0; r < 4; ++r) {
    const int qg = q0 + mb * 16 + (l >> 4) * 4 + r;
    const int dd = nb * 16 + (l & 15);
    OUT1[((size_t)b * 1024 + qg) * 512 + h * 64 + dd] = (f16)oacc[mb][nb][r];
  }
}

// ---------------- Kernel D: out = OUT1 @ w_out + b_out ----------------
__global__ __launch_bounds__(256) void kout(
    const f16* __restrict__ OUT1, const float* __restrict__ w_out,
    const float* __restrict__ b_out, float* __restrict__ out)
{
  __shared__ f16 a_s[128][36];
  __shared__ f16 b_s[64][36];
  const int t = threadIdx.x, l = t & 63, w = t >> 6;
  const int m0 = blockIdx.x * 128;
  const int c0 = blockIdx.y * 64;
  f32x4 acc[2][4] = {};
  for (int k0 = 0; k0 < 512; k0 += 32) {
    __syncthreads();
    #pragma unroll
    for (int rep = 0; rep < 2; ++rep) {
      int idx = rep * 2048 + t * 8;
      int r = idx >> 5, c = idx & 31;
      f16x8 v = *(const f16x8*)&OUT1[(size_t)(m0 + r) * 512 + k0 + c];
      *(f16x4*)&a_s[r][c]     = f16x4{v[0], v[1], v[2], v[3]};
      *(f16x4*)&a_s[r][c + 4] = f16x4{v[4], v[5], v[6], v[7]};
    }
    #pragma unroll
    for (int rep = 0; rep < 2; ++rep) {
      int idx = rep * 1024 + t * 4;
      int kr = idx >> 6, c = idx & 63;
      float4 v = *(const float4*)&w_out[(size_t)(k0 + kr) * 512 + c0 + c];
      b_s[c + 0][kr] = (f16)v.x; b_s[c + 1][kr] = (f16)v.y;
      b_s[c + 2][kr] = (f16)v.z; b_s[c + 3][kr] = (f16)v.w;
    }
    __syncthreads();
    const int kc = (l >> 4) * 8;
    f16x8 af[2];
    #pragma unroll
    for (int mb = 0; mb < 2; ++mb) {
      int r = w * 32 + mb * 16 + (l & 15);
      af[mb] = cat8(*(const f16x4*)&a_s[r][kc], *(const f16x4*)&a_s[r][kc + 4]);
    }
    #pragma unroll
    for (int nb = 0; nb < 4; ++nb) {
      int cc = nb * 16 + (l & 15);
      f16x8 bf = cat8(*(const f16x4*)&b_s[cc][kc], *(const f16x4*)&b_s[cc][kc + 4]);
      #pragma unroll
      for (int mb = 0; mb < 2; ++mb)
        acc[mb][nb] = MFMA16(af[mb], bf, acc[mb][nb]);
    }
  }
  #pragma unroll
  for (int mb = 0; mb < 2; ++mb)
  #pragma unroll
  for (int nb = 0; nb < 4; ++nb) {
    const int cg = c0 + nb * 16 + (l & 15);
    const float bb = b_out[cg];
    #pragma unroll
    for (int r = 0; r < 4; ++r) {
      const int m = m0 + w * 32 + mb * 16 + (l >> 4) * 4 + r;
      out[(size_t)m * 512 + cg] = acc[mb][nb][r] + bb;
    }
  }
}

extern "C" void kernel_launch(void* const* d_in, const int* in_sizes, int n_in,
                              void* d_out, int out_size, void* d_ws, size_t ws_size,
                              hipStream_t stream) {
  const float* x       = (const float*)d_in[0];
  const float* rt      = (const float*)d_in[1];
  const float* rc      = (const float*)d_in[2];
  const float* bias_te = (const float*)d_in[3];
  const float* w_qkv   = (const float*)d_in[7];
  const float* w_kr_t  = (const float*)d_in[8];
  const float* w_kr_c  = (const float*)d_in[9];
  const float* w_out   = (const float*)d_in[10];
  const float* b_out   = (const float*)d_in[11];
  float* out = (float*)d_out;
  float* attn_out = out + (size_t)8 * 1024 * 512;

  const size_t NEEDED = 176160768;  // bytes of f16 workspace
  if (ws_size < NEEDED) return;     // ws too small: bail (will show as wrong output)
  f16* ws   = (f16*)d_ws;
  f16* QB   = ws;
  f16* Kf   = QB + 4194304;
  f16* VT   = Kf + 4194304;
  f16* WRS  = VT + 4194304;
  f16* OUT1 = WRS + 4194304;
  f16* BD   = OUT1 + 4194304;  // 67108864 elements

  kproj<<<dim3(64, 32), 256, 0, stream>>>(x, rt, rc, w_qkv, w_kr_t, w_kr_c, bias_te,
                                          QB, Kf, VT, WRS);
  krel<<<dim3(16, 16, 64), 256, 0, stream>>>(QB, WRS, BD);
  kattn<<<dim3(256), 512, 0, stream>>>(QB, Kf, VT, BD, attn_out, OUT1);
  kout<<<dim3(64, 8), 256, 0, stream>>>(OUT1, w_out, b_out, out);
}

// Round 2
// 437.385 us; speedup vs baseline: 1.0475x; 1.0475x over previous
//
#include <hip/hip_runtime.h>
#include <hip/hip_fp16.h>

// B=8, N=1024, E=512, H=8, D=64
// ws layout (f16): QB[64][1024][64], K[64][1024][64], VT[64][64][1024],
//                  WRS[64][1024][64], OUT1[8192][512], BD[64][1024][1024]

typedef _Float16 f16;
typedef f16 f16x4 __attribute__((ext_vector_type(4)));
typedef f16 f16x8 __attribute__((ext_vector_type(8)));
typedef float f32x4 __attribute__((ext_vector_type(4)));

#define MFMA16(a,b,c) __builtin_amdgcn_mfma_f32_16x16x32_f16((a),(b),(c),0,0,0)

static __device__ __forceinline__ f16x8 cat8(f16x4 lo, f16x4 hi) {
  return __builtin_shufflevector(lo, hi, 0, 1, 2, 3, 4, 5, 6, 7);
}

// ---------------- Kernel A: projections ----------------
__global__ __launch_bounds__(256) void kproj(
    const float* __restrict__ x, const float* __restrict__ rt, const float* __restrict__ rc,
    const float* __restrict__ wqkv, const float* __restrict__ wkrt, const float* __restrict__ wkrc,
    const float* __restrict__ bias_te,
    f16* __restrict__ QB, f16* __restrict__ Kf, f16* __restrict__ VT, f16* __restrict__ WRS)
{
  __shared__ f16 a_s[128][36];
  __shared__ f16 b_s[64][36];
  const int t = threadIdx.x, l = t & 63, w = t >> 6;
  const int m0 = blockIdx.x * 128;
  const int c0 = blockIdx.y * 64;
  const int mode = c0 >> 9;  // 0:Q 1:K 2:V 3:WRS
  f32x4 acc[2][4] = {};
  const int nsrc = (mode == 3) ? 2 : 1;
  for (int src = 0; src < nsrc; ++src) {
    const float* Ap = (mode == 3) ? (src ? rc : rt) : x;
    const float* Bp = (mode == 3) ? (src ? wkrc : wkrt) : wqkv;
    const int bstride = (mode == 3) ? 512 : 1536;
    const int bc0 = (mode == 3) ? (c0 - 1536) : c0;
    for (int k0 = 0; k0 < 512; k0 += 32) {
      __syncthreads();
      #pragma unroll
      for (int rep = 0; rep < 4; ++rep) {
        int idx = rep * 1024 + t * 4;
        int r = idx >> 5, c = idx & 31;
        float4 v = *(const float4*)&Ap[(size_t)(m0 + r) * 512 + k0 + c];
        *(f16x4*)&a_s[r][c] = f16x4{(f16)v.x, (f16)v.y, (f16)v.z, (f16)v.w};
      }
      #pragma unroll
      for (int rep = 0; rep < 2; ++rep) {
        int idx = rep * 1024 + t * 4;
        int kr = idx >> 6, c = idx & 63;
        float4 v = *(const float4*)&Bp[(size_t)(k0 + kr) * bstride + bc0 + c];
        b_s[c + 0][kr] = (f16)v.x; b_s[c + 1][kr] = (f16)v.y;
        b_s[c + 2][kr] = (f16)v.z; b_s[c + 3][kr] = (f16)v.w;
      }
      __syncthreads();
      const int kc = (l >> 4) * 8;
      f16x8 af[2];
      #pragma unroll
      for (int mb = 0; mb < 2; ++mb) {
        int r = w * 32 + mb * 16 + (l & 15);
        af[mb] = cat8(*(const f16x4*)&a_s[r][kc], *(const f16x4*)&a_s[r][kc + 4]);
      }
      #pragma unroll
      for (int nb = 0; nb < 4; ++nb) {
        int cc = nb * 16 + (l & 15);
        f16x8 bf = cat8(*(const f16x4*)&b_s[cc][kc], *(const f16x4*)&b_s[cc][kc + 4]);
        #pragma unroll
        for (int mb = 0; mb < 2; ++mb)
          acc[mb][nb] = MFMA16(af[mb], bf, acc[mb][nb]);
      }
    }
  }
  #pragma unroll
  for (int mb = 0; mb < 2; ++mb)
  #pragma unroll
  for (int nb = 0; nb < 4; ++nb) {
    const int cg = c0 + nb * 16 + (l & 15);
    const int mbase = m0 + w * 32 + mb * 16 + (l >> 4) * 4;
    const int bb = mbase >> 10, nbase = mbase & 1023;
    if (mode == 2) {
      const int cv = cg - 1024, hh = cv >> 6, dd = cv & 63;
      f32x4 a = acc[mb][nb];
      *(f16x4*)&VT[(((size_t)bb * 8 + hh) * 64 + dd) * 1024 + nbase] =
          f16x4{(f16)a[0], (f16)a[1], (f16)a[2], (f16)a[3]};
    } else {
      f16* outp; int cl; float badd = 0.f;
      if (mode == 0) { outp = QB; cl = cg; badd = bias_te[cg]; }
      else if (mode == 1) { outp = Kf; cl = cg - 512; }
      else { outp = WRS; cl = cg - 1536; }
      const int hh = cl >> 6, dd = cl & 63;
      #pragma unroll
      for (int r = 0; r < 4; ++r)
        outp[(((size_t)bb * 8 + hh) * 1024 + (nbase + r)) * 64 + dd] =
            (f16)(acc[mb][nb][r] + badd);
    }
  }
}

// ---------------- Kernel B: rawsum GEMM + rel_shift scatter (128x128 tiles) ----
// Writes BD pre-scaled by 0.5. (q,q+1) slots never written -> masked in kdots.
__global__ __launch_bounds__(256) void krel(
    const f16* __restrict__ QB, const f16* __restrict__ WRS, f16* __restrict__ BD)
{
  const int t = threadIdx.x, l = t & 63, w = t >> 6;
  const int j0 = blockIdx.x * 128;
  const int i0 = blockIdx.y * 128;
  const int bh = blockIdx.z;
  const int wr = w >> 1, wc = w & 1;
  const size_t base = (size_t)bh * 65536;
  const size_t bdb = (size_t)bh << 20;
  f32x4 acc[4][4] = {};
  #pragma unroll
  for (int kc = 0; kc < 2; ++kc) {
    const int dc = kc * 32 + (l >> 4) * 8;
    f16x8 af[4], bf[4];
    #pragma unroll
    for (int mb = 0; mb < 4; ++mb)
      af[mb] = *(const f16x8*)&QB[base + (size_t)(i0 + wr * 64 + mb * 16 + (l & 15)) * 64 + dc];
    #pragma unroll
    for (int nb = 0; nb < 4; ++nb)
      bf[nb] = *(const f16x8*)&WRS[base + (size_t)(j0 + wc * 64 + nb * 16 + (l & 15)) * 64 + dc];
    #pragma unroll
    for (int mb = 0; mb < 4; ++mb)
    #pragma unroll
    for (int nb = 0; nb < 4; ++nb)
      acc[mb][nb] = MFMA16(af[mb], bf[nb], acc[mb][nb]);
  }
  #pragma unroll
  for (int mb = 0; mb < 4; ++mb)
  #pragma unroll
  for (int nb = 0; nb < 4; ++nb)
  #pragma unroll
  for (int r = 0; r < 4; ++r) {
    const int i = i0 + wr * 64 + mb * 16 + (l >> 4) * 4 + r;
    const int j = j0 + wc * 64 + nb * 16 + (l & 15);
    const int s = i + j;
    int q, k;
    if (s >= 1023) { q = i; k = s - 1023; }
    else           { q = i - 1; k = s + 1; }
    if (q >= 0) BD[bdb + (size_t)q * 1024 + k] = (f16)(0.5f * acc[mb][nb][r]);
  }
}

// ---------------- Kernel C1: dots = AC + BD, softmax over h, write attn ------
// grid (ktile 16, qtile 32, b 8) = 4096 blocks; 512 threads, wave = head.
__global__ __launch_bounds__(512) void kdots(
    const f16* __restrict__ QB, const f16* __restrict__ Kf,
    const f16* __restrict__ BD, float* __restrict__ attn_out)
{
  __shared__ f16 sd[8][32][72];
  const int t = threadIdx.x, l = t & 63, h = t >> 6;
  const int k0 = blockIdx.x * 64;
  const int q0 = blockIdx.y * 32;
  const int b = blockIdx.z;
  const int bh = b * 8 + h;
  const size_t base = (size_t)bh * 65536;
  const size_t bdb = (size_t)bh << 20;
  // Q fragments
  f16x8 aq[2][2];
  #pragma unroll
  for (int mb = 0; mb < 2; ++mb)
  #pragma unroll
  for (int kc = 0; kc < 2; ++kc) {
    int qg = q0 + mb * 16 + (l & 15);
    int dc = kc * 32 + (l >> 4) * 8;
    aq[mb][kc] = *(const f16x8*)&QB[base + (size_t)qg * 64 + dc];
  }
  // BD prefetch (pre-scaled by 0.5 in krel)
  f16x8 bdv[4];
  #pragma unroll
  for (int s = 0; s < 4; ++s) {
    const int o = s * 512 + l * 8;
    const int q = o >> 6, k = o & 63;
    bdv[s] = *(const f16x8*)&BD[bdb + (size_t)(q0 + q) * 1024 + k0 + k];
  }
  // AC
  f32x4 acc[2][4] = {};
  #pragma unroll
  for (int kc = 0; kc < 2; ++kc) {
    const int dc = kc * 32 + (l >> 4) * 8;
    #pragma unroll
    for (int nb = 0; nb < 4; ++nb) {
      int jg = k0 + nb * 16 + (l & 15);
      f16x8 bf = *(const f16x8*)&Kf[base + (size_t)jg * 64 + dc];
      #pragma unroll
      for (int mb = 0; mb < 2; ++mb)
        acc[mb][nb] = MFMA16(aq[mb][kc], bf, acc[mb][nb]);
    }
  }
  #pragma unroll
  for (int mb = 0; mb < 2; ++mb)
  #pragma unroll
  for (int nb = 0; nb < 4; ++nb)
  #pragma unroll
  for (int r = 0; r < 4; ++r)
    sd[h][mb * 16 + (l >> 4) * 4 + r][nb * 16 + (l & 15)] = (f16)acc[mb][nb][r];
  __syncthreads();
  // dots += BD (mask the k==q+1 rel-shift zero slot)
  #pragma unroll
  for (int s = 0; s < 4; ++s) {
    const int o = s * 512 + l * 8;
    const int q = o >> 6, k = o & 63;
    f16x8 cur = *(f16x8*)&sd[h][q][k];
    const int qg1 = q0 + q + 1;
    #pragma unroll
    for (int e = 0; e < 8; ++e) {
      float vv = (float)cur[e];
      if (k0 + k + e != qg1) vv += (float)bdv[s][e];
      cur[e] = (f16)vv;
    }
    *(f16x8*)&sd[h][q][k] = cur;
  }
  __syncthreads();
  // softmax over heads + attn write
  {
    const int o = t * 4, q = o >> 6, k = o & 63;
    float dv[8][4];
    #pragma unroll
    for (int hh = 0; hh < 8; ++hh) {
      f16x4 v = *(const f16x4*)&sd[hh][q][k];
      dv[hh][0] = (float)v[0]; dv[hh][1] = (float)v[1];
      dv[hh][2] = (float)v[2]; dv[hh][3] = (float)v[3];
    }
    #pragma unroll
    for (int e = 0; e < 4; ++e) {
      float m = dv[0][e];
      #pragma unroll
      for (int hh = 1; hh < 8; ++hh) m = fmaxf(m, dv[hh][e]);
      float ssum = 0.f;
      #pragma unroll
      for (int hh = 0; hh < 8; ++hh) { float a = __expf(dv[hh][e] - m); dv[hh][e] = a; ssum += a; }
      float rinv = 1.f / ssum;
      #pragma unroll
      for (int hh = 0; hh < 8; ++hh) dv[hh][e] *= rinv;
    }
    const size_t qg = q0 + q;
    #pragma unroll
    for (int hh = 0; hh < 8; ++hh)
      *(float4*)&attn_out[((size_t)(b * 8 + hh) * 1024 + qg) * 1024 + k0 + k] =
          float4{dv[hh][0], dv[hh][1], dv[hh][2], dv[hh][3]};
  }
}

// ---------------- Kernel C2: PV = attn @ V -> OUT1 ----------------
// grid (qtile 8, bh 64), 256 threads (4 waves, 32 q-rows each).
__global__ __launch_bounds__(256) void kpv(
    const float* __restrict__ attn, const f16* __restrict__ VT, f16* __restrict__ OUT1)
{
  __shared__ f16 at[128][72];
  const int t = threadIdx.x, l = t & 63, w = t >> 6;
  const int q0 = blockIdx.x * 128;
  const int bh = blockIdx.y;
  const int b = bh >> 3, h = bh & 7;
  const size_t abase = (size_t)bh * 1024 * 1024;
  const size_t vbase = (size_t)bh * 65536;
  f32x4 acc[2][4] = {};
  for (int j0 = 0; j0 < 1024; j0 += 64) {
    __syncthreads();
    #pragma unroll
    for (int rep = 0; rep < 8; ++rep) {
      int idx = rep * 1024 + t * 4;
      int q = idx >> 6, j = idx & 63;
      float4 v = *(const float4*)&attn[abase + (size_t)(q0 + q) * 1024 + j0 + j];
      *(f16x4*)&at[q][j] = f16x4{(f16)v.x, (f16)v.y, (f16)v.z, (f16)v.w};
    }
    __syncthreads();
    #pragma unroll
    for (int kc = 0; kc < 2; ++kc) {
      f16x8 pa[2];
      #pragma unroll
      for (int mb = 0; mb < 2; ++mb) {
        int row = w * 32 + mb * 16 + (l & 15);
        int jj = kc * 32 + (l >> 4) * 8;
        pa[mb] = *(const f16x8*)&at[row][jj];
      }
      #pragma unroll
      for (int nb = 0; nb < 4; ++nb) {
        int dd = nb * 16 + (l & 15);
        int jg = j0 + kc * 32 + (l >> 4) * 8;
        f16x8 vb = *(const f16x8*)&VT[vbase + (size_t)dd * 1024 + jg];
        #pragma unroll
        for (int mb = 0; mb < 2; ++mb)
          acc[mb][nb] = MFMA16(pa[mb], vb, acc[mb][nb]);
      }
    }
  }
  #pragma unroll
  for (int mb = 0; mb < 2; ++mb)
  #pragma unroll
  for (int nb = 0; nb < 4; ++nb)
  #pragma unroll
  for (int r = 0; r < 4; ++r) {
    const int qg = q0 + w * 32 + mb * 16 + (l >> 4) * 4 + r;
    const int dd = nb * 16 + (l & 15);
    OUT1[((size_t)b * 1024 + qg) * 512 + h * 64 + dd] = (f16)acc[mb][nb][r];
  }
}

// ---------------- Kernel D: out = OUT1 @ w_out + b_out ----------------
__global__ __launch_bounds__(256) void kout(
    const f16* __restrict__ OUT1, const float* __restrict__ w_out,
    const float* __restrict__ b_out, float* __restrict__ out)
{
  __shared__ f16 a_s[128][36];
  __shared__ f16 b_s[64][36];
  const int t = threadIdx.x, l = t & 63, w = t >> 6;
  const int m0 = blockIdx.x * 128;
  const int c0 = blockIdx.y * 64;
  f32x4 acc[2][4] = {};
  for (int k0 = 0; k0 < 512; k0 += 32) {
    __syncthreads();
    #pragma unroll
    for (int rep = 0; rep < 2; ++rep) {
      int idx = rep * 2048 + t * 8;
      int r = idx >> 5, c = idx & 31;
      f16x8 v = *(const f16x8*)&OUT1[(size_t)(m0 + r) * 512 + k0 + c];
      *(f16x4*)&a_s[r][c]     = f16x4{v[0], v[1], v[2], v[3]};
      *(f16x4*)&a_s[r][c + 4] = f16x4{v[4], v[5], v[6], v[7]};
    }
    #pragma unroll
    for (int rep = 0; rep < 2; ++rep) {
      int idx = rep * 1024 + t * 4;
      int kr = idx >> 6, c = idx & 63;
      float4 v = *(const float4*)&w_out[(size_t)(k0 + kr) * 512 + c0 + c];
      b_s[c + 0][kr] = (f16)v.x; b_s[c + 1][kr] = (f16)v.y;
      b_s[c + 2][kr] = (f16)v.z; b_s[c + 3][kr] = (f16)v.w;
    }
    __syncthreads();
    const int kc = (l >> 4) * 8;
    f16x8 af[2];
    #pragma unroll
    for (int mb = 0; mb < 2; ++mb) {
      int r = w * 32 + mb * 16 + (l & 15);
      af[mb] = cat8(*(const f16x4*)&a_s[r][kc], *(const f16x4*)&a_s[r][kc + 4]);
    }
    #pragma unroll
    for (int nb = 0; nb < 4; ++nb) {
      int cc = nb * 16 + (l & 15);
      f16x8 bf = cat8(*(const f16x4*)&b_s[cc][kc], *(const f16x4*)&b_s[cc][kc + 4]);
      #pragma unroll
      for (int mb = 0; mb < 2; ++mb)
        acc[mb][nb] = MFMA16(af[mb], bf, acc[mb][nb]);
    }
  }
  #pragma unroll
  for (int mb = 0; mb < 2; ++mb)
  #pragma unroll
  for (int nb = 0; nb < 4; ++nb) {
    const int cg = c0 + nb * 16 + (l & 15);
    const float bb = b_out[cg];
    #pragma unroll
    for (int r = 0; r < 4; ++r) {
      const int m = m0 + w * 32 + mb * 16 + (l >> 4) * 4 + r;
      out[(size_t)m * 512 + cg] = acc[mb][nb][r] + bb;
    }
  }
}

extern "C" void kernel_launch(void* const* d_in, const int* in_sizes, int n_in,
                              void* d_out, int out_size, void* d_ws, size_t ws_size,
                              hipStream_t stream) {
  const float* x       = (const float*)d_in[0];
  const float* rt      = (const float*)d_in[1];
  const float* rc      = (const float*)d_in[2];
  const float* bias_te = (const float*)d_in[3];
  const float* w_qkv   = (const float*)d_in[7];
  const float* w_kr_t  = (const float*)d_in[8];
  const float* w_kr_c  = (const float*)d_in[9];
  const float* w_out   = (const float*)d_in[10];
  const float* b_out   = (const float*)d_in[11];
  float* out = (float*)d_out;
  float* attn_out = out + (size_t)8 * 1024 * 512;

  const size_t NEEDED = 176160768;
  if (ws_size < NEEDED) return;
  f16* ws   = (f16*)d_ws;
  f16* QB   = ws;
  f16* Kf   = QB + 4194304;
  f16* VT   = Kf + 4194304;
  f16* WRS  = VT + 4194304;
  f16* OUT1 = WRS + 4194304;
  f16* BD   = OUT1 + 4194304;

  kproj<<<dim3(64, 32), 256, 0, stream>>>(x, rt, rc, w_qkv, w_kr_t, w_kr_c, bias_te,
                                          QB, Kf, VT, WRS);
  krel<<<dim3(8, 8, 64), 256, 0, stream>>>(QB, WRS, BD);
  kdots<<<dim3(16, 32, 8), 512, 0, stream>>>(QB, Kf, BD, attn_out);
  kpv<<<dim3(8, 64), 256, 0, stream>>>(attn_out, VT, OUT1);
  kout<<<dim3(64, 8), 256, 0, stream>>>(OUT1, w_out, b_out, out);
}

// Round 3
// 331.260 us; speedup vs baseline: 1.3831x; 1.3204x over previous
//
#include <hip/hip_runtime.h>
#include <hip/hip_fp16.h>

// B=8, N=1024, E=512, H=8, D=64
// ws (f16): X16[8192][512], A2[8192][1024], WQ[1536][512], W2[512][1024],
//           QP/KP/WP packed A/B-frag [64bh][64ft][2kc][64lane][8], VP packed,
//           OUT1[8192][512], BD[64][1024][1024]

typedef _Float16 f16;
typedef f16 f16x4 __attribute__((ext_vector_type(4)));
typedef f16 f16x8 __attribute__((ext_vector_type(8)));
typedef float f32x4 __attribute__((ext_vector_type(4)));

#define MFMA16(a,b,c) __builtin_amdgcn_mfma_f32_16x16x32_f16((a),(b),(c),0,0,0)

// packed index helpers: QP/KP/WP element (bh, token q, d); VP element (bh, d, token j)
static __device__ __forceinline__ size_t qpidx(int bh, int q, int d) {
  return ((((size_t)bh * 64 + (q >> 4)) * 2 + (d >> 5)) * 64 +
          ((q & 15) + (((d >> 3) & 3) << 4))) * 8 + (d & 7);
}
static __device__ __forceinline__ size_t vpidx(int bh, int d, int j) {
  return ((((size_t)bh * 4 + (d >> 4)) * 32 + (j >> 5)) * 64 +
          ((d & 15) + (((j >> 3) & 3) << 4))) * 8 + (j & 7);
}

// ---------------- Kernel 0: prep (convert + concat + transpose weights) -----
__global__ __launch_bounds__(256) void kprep(
    const float* __restrict__ x, const float* __restrict__ rt, const float* __restrict__ rc,
    const float* __restrict__ wqkv, const float* __restrict__ wkrt, const float* __restrict__ wkrc,
    f16* __restrict__ X16, f16* __restrict__ A2, f16* __restrict__ WQ, f16* __restrict__ W2)
{
  const int t = threadIdx.x, gx = blockIdx.x, mode = blockIdx.y;
  if (mode <= 2) {
    const size_t id = (size_t)gx * 256 + t;  // 524288 chunks of 8
    const float* src = (mode == 0) ? x : (mode == 1) ? rt : rc;
    float4 v0 = *(const float4*)&src[id * 8];
    float4 v1 = *(const float4*)&src[id * 8 + 4];
    f16x8 o = {(f16)v0.x, (f16)v0.y, (f16)v0.z, (f16)v0.w,
               (f16)v1.x, (f16)v1.y, (f16)v1.z, (f16)v1.w};
    if (mode == 0) *(f16x8*)&X16[id * 8] = o;
    else {
      const int mrow = (int)(id >> 6), cc = (int)(id & 63);
      *(f16x8*)&A2[(size_t)mrow * 1024 + (mode == 2 ? 512 : 0) + cc * 8] = o;
    }
  } else if (mode == 3) {      // WQ[n][k] = wqkv[k][n], f16
    if (gx >= 384) return;
    const int c = gx & 63, n = (gx >> 6) * 256 + t;
    f16x8 o;
    #pragma unroll
    for (int e = 0; e < 8; ++e) o[e] = (f16)wqkv[(size_t)(c * 8 + e) * 1536 + n];
    *(f16x8*)&WQ[(size_t)n * 512 + c * 8] = o;
  } else {                     // W2[n][k<512]=wkrt[k][n]; W2[n][512+k]=wkrc[k][n]
    if (gx >= 128) return;
    const int c = gx & 63, n = (gx >> 6) * 256 + t;
    const float* src = (mode == 4) ? wkrt : wkrc;
    f16x8 o;
    #pragma unroll
    for (int e = 0; e < 8; ++e) o[e] = (f16)src[(size_t)(c * 8 + e) * 512 + n];
    *(f16x8*)&W2[(size_t)n * 1024 + (mode == 5 ? 512 : 0) + c * 8] = o;
  }
}

// ---------------- Kernel A: projections (128x128 tile, BK=64, swizzled LDS) --
// grid (64 mtile, 16 ntile): y 0-3 Q, 4-7 K, 8-11 V, 12-15 WRS(K=1024)
__global__ __launch_bounds__(256) void kproj(
    const f16* __restrict__ X16, const f16* __restrict__ A2,
    const f16* __restrict__ WQ, const f16* __restrict__ W2,
    const float* __restrict__ bias_te,
    f16* __restrict__ QP, f16* __restrict__ KP, f16* __restrict__ VP, f16* __restrict__ WP)
{
  __shared__ f16 As[128 * 64];
  __shared__ f16 Bs[128 * 64];
  const int t = threadIdx.x, l = t & 63, w = t >> 6;
  const int wr = w >> 1, wc = w & 1;
  const int m0 = blockIdx.x * 128;
  const int y = blockIdx.y;
  const int mode = y >> 2;               // 0:Q 1:K 2:V 3:WRS
  const bool wrs = (mode == 3);
  const f16* Asrc = wrs ? A2 : X16;
  const int lda = wrs ? 1024 : 512;
  const int K = wrs ? 1024 : 512;
  const f16* Bsrc = wrs ? (W2 + (size_t)((y - 12) * 128) * 1024)
                        : (WQ + (size_t)(y * 128) * 512);
  const int ldb = wrs ? 1024 : 512;

  f32x4 acc[4][4] = {};
  for (int k0 = 0; k0 < K; k0 += 64) {
    __syncthreads();
    #pragma unroll
    for (int rep = 0; rep < 4; ++rep) {
      const int idx = rep * 256 + t;       // 1024 chunks: row=idx>>3, kb=idx&7
      const int row = idx >> 3, kb = idx & 7;
      const int slot = (kb ^ (row & 7)) << 3;
      f16x8 va = *(const f16x8*)&Asrc[(size_t)(m0 + row) * lda + k0 + kb * 8];
      *(f16x8*)&As[row * 64 + slot] = va;
      f16x8 vb = *(const f16x8*)&Bsrc[(size_t)row * ldb + k0 + kb * 8];
      *(f16x8*)&Bs[row * 64 + slot] = vb;
    }
    __syncthreads();
    #pragma unroll
    for (int kc = 0; kc < 2; ++kc) {
      f16x8 af[4], bf[4];
      const int kb = kc * 4 + (l >> 4);
      #pragma unroll
      for (int mb = 0; mb < 4; ++mb) {
        const int r = wr * 64 + mb * 16 + (l & 15);
        af[mb] = *(const f16x8*)&As[r * 64 + ((kb ^ (r & 7)) << 3)];
      }
      #pragma unroll
      for (int nb = 0; nb < 4; ++nb) {
        const int r = wc * 64 + nb * 16 + (l & 15);
        bf[nb] = *(const f16x8*)&Bs[r * 64 + ((kb ^ (r & 7)) << 3)];
      }
      #pragma unroll
      for (int mb = 0; mb < 4; ++mb)
      #pragma unroll
      for (int nb = 0; nb < 4; ++nb)
        acc[mb][nb] = MFMA16(af[mb], bf[nb], acc[mb][nb]);
    }
  }
  // epilogue: scatter into fragment-packed layouts (scalar f16 stores; L2 merges)
  #pragma unroll
  for (int mb = 0; mb < 4; ++mb)
  #pragma unroll
  for (int nb = 0; nb < 4; ++nb) {
    const int loc = wc * 64 + nb * 16 + (l & 15);
    const int c = (y & 3) * 128 + loc;   // 0..511 within the mode
    const int hh = c >> 6, d = c & 63;
    const float badd = (mode == 0) ? bias_te[c] : 0.f;
    f32x4 a = acc[mb][nb];
    #pragma unroll
    for (int r = 0; r < 4; ++r) {
      const int m = m0 + wr * 64 + mb * 16 + (l >> 4) * 4 + r;
      const int bb = m >> 10, tn = m & 1023;
      const int bh = bb * 8 + hh;
      const float v = a[r] + badd;
      if (mode == 0)      QP[qpidx(bh, tn, d)] = (f16)v;
      else if (mode == 1) KP[qpidx(bh, tn, d)] = (f16)v;
      else if (mode == 2) VP[vpidx(bh, d, tn)] = (f16)v;
      else                WP[qpidx(bh, tn, d)] = (f16)v;
    }
  }
}

// ---------------- Kernel B: rawsum GEMM + rel_shift (linear-dest form) -------
// dst linear = i*1024 + (i+j-1023); negative -> dropped. Pre-scaled by 0.5.
__global__ __launch_bounds__(256) void krel(
    const f16* __restrict__ QP, const f16* __restrict__ WP, f16* __restrict__ BD)
{
  const int t = threadIdx.x, l = t & 63, w = t >> 6;
  const int j0 = blockIdx.x * 128, i0 = blockIdx.y * 128, bh = blockIdx.z;
  const int wr = w >> 1, wc = w & 1;
  const f16x8* QP8 = (const f16x8*)QP;
  const f16x8* WP8 = (const f16x8*)WP;
  f32x4 acc[4][4] = {};
  #pragma unroll
  for (int kc = 0; kc < 2; ++kc) {
    f16x8 af[4], bf[4];
    #pragma unroll
    for (int mb = 0; mb < 4; ++mb)
      af[mb] = QP8[((size_t)(bh * 64 + (i0 >> 4) + wr * 4 + mb) * 2 + kc) * 64 + l];
    #pragma unroll
    for (int nb = 0; nb < 4; ++nb)
      bf[nb] = WP8[((size_t)(bh * 64 + (j0 >> 4) + wc * 4 + nb) * 2 + kc) * 64 + l];
    #pragma unroll
    for (int mb = 0; mb < 4; ++mb)
    #pragma unroll
    for (int nb = 0; nb < 4; ++nb)
      acc[mb][nb] = MFMA16(af[mb], bf[nb], acc[mb][nb]);
  }
  const size_t bdb = (size_t)bh << 20;
  #pragma unroll
  for (int mb = 0; mb < 4; ++mb)
  #pragma unroll
  for (int nb = 0; nb < 4; ++nb)
  #pragma unroll
  for (int r = 0; r < 4; ++r) {
    const int i = i0 + wr * 64 + mb * 16 + (l >> 4) * 4 + r;
    const int j = j0 + wc * 64 + nb * 16 + (l & 15);
    const int d = i * 1024 + i + j - 1023;
    if (d >= 0) BD[bdb + (size_t)d] = (f16)(0.5f * acc[mb][nb][r]);
  }
}

// ---------------- Kernel C1: dots = AC + BD, softmax over h, write attn ------
// grid (ktile 16, qtile 32, b 8); 512 threads, wave = head.
__global__ __launch_bounds__(512) void kdots(
    const f16* __restrict__ QP, const f16* __restrict__ KP,
    const f16* __restrict__ BD, float* __restrict__ attn_out)
{
  __shared__ f16 sd[8][32][72];
  const int t = threadIdx.x, l = t & 63, h = t >> 6;
  const int k0 = blockIdx.x * 64;
  const int q0 = blockIdx.y * 32;
  const int b = blockIdx.z;
  const int bh = b * 8 + h;
  const size_t bdb = (size_t)bh << 20;
  const f16x8* QP8 = (const f16x8*)QP;
  const f16x8* KP8 = (const f16x8*)KP;
  // Q fragments (coalesced packed reads)
  f16x8 aq[2][2];
  #pragma unroll
  for (int mb = 0; mb < 2; ++mb)
  #pragma unroll
  for (int kc = 0; kc < 2; ++kc)
    aq[mb][kc] = QP8[((size_t)(bh * 64 + (q0 >> 4) + mb) * 2 + kc) * 64 + l];
  // BD prefetch (pre-scaled by 0.5 in krel)
  f16x8 bdv[4];
  #pragma unroll
  for (int s = 0; s < 4; ++s) {
    const int o = s * 512 + l * 8;
    const int q = o >> 6, k = o & 63;
    bdv[s] = *(const f16x8*)&BD[bdb + (size_t)(q0 + q) * 1024 + k0 + k];
  }
  // AC
  f32x4 acc[2][4] = {};
  #pragma unroll
  for (int kc = 0; kc < 2; ++kc) {
    #pragma unroll
    for (int nb = 0; nb < 4; ++nb) {
      f16x8 bf = KP8[((size_t)(bh * 64 + (k0 >> 4) + nb) * 2 + kc) * 64 + l];
      #pragma unroll
      for (int mb = 0; mb < 2; ++mb)
        acc[mb][nb] = MFMA16(aq[mb][kc], bf, acc[mb][nb]);
    }
  }
  #pragma unroll
  for (int mb = 0; mb < 2; ++mb)
  #pragma unroll
  for (int nb = 0; nb < 4; ++nb)
  #pragma unroll
  for (int r = 0; r < 4; ++r)
    sd[h][mb * 16 + (l >> 4) * 4 + r][nb * 16 + (l & 15)] = (f16)acc[mb][nb][r];
  __syncthreads();
  // dots += BD (mask the k==q+1 rel-shift zero slot)
  #pragma unroll
  for (int s = 0; s < 4; ++s) {
    const int o = s * 512 + l * 8;
    const int q = o >> 6, k = o & 63;
    f16x8 cur = *(f16x8*)&sd[h][q][k];
    const int qg1 = q0 + q + 1;
    #pragma unroll
    for (int e = 0; e < 8; ++e) {
      float vv = (float)cur[e];
      if (k0 + k + e != qg1) vv += (float)bdv[s][e];
      cur[e] = (f16)vv;
    }
    *(f16x8*)&sd[h][q][k] = cur;
  }
  __syncthreads();
  // softmax over heads + attn write
  {
    const int o = t * 4, q = o >> 6, k = o & 63;
    float dv[8][4];
    #pragma unroll
    for (int hh = 0; hh < 8; ++hh) {
      f16x4 v = *(const f16x4*)&sd[hh][q][k];
      dv[hh][0] = (float)v[0]; dv[hh][1] = (float)v[1];
      dv[hh][2] = (float)v[2]; dv[hh][3] = (float)v[3];
    }
    #pragma unroll
    for (int e = 0; e < 4; ++e) {
      float m = dv[0][e];
      #pragma unroll
      for (int hh = 1; hh < 8; ++hh) m = fmaxf(m, dv[hh][e]);
      float ssum = 0.f;
      #pragma unroll
      for (int hh = 0; hh < 8; ++hh) { float a = __expf(dv[hh][e] - m); dv[hh][e] = a; ssum += a; }
      float rinv = 1.f / ssum;
      #pragma unroll
      for (int hh = 0; hh < 8; ++hh) dv[hh][e] *= rinv;
    }
    const size_t qg = q0 + q;
    #pragma unroll
    for (int hh = 0; hh < 8; ++hh)
      *(float4*)&attn_out[((size_t)(b * 8 + hh) * 1024 + qg) * 1024 + k0 + k] =
          float4{dv[hh][0], dv[hh][1], dv[hh][2], dv[hh][3]};
  }
}

// ---------------- Kernel C2: PV = attn @ V -> OUT1 ----------------
__global__ __launch_bounds__(256) void kpv(
    const float* __restrict__ attn, const f16* __restrict__ VP, f16* __restrict__ OUT1)
{
  __shared__ f16 at[128][72];
  const int t = threadIdx.x, l = t & 63, w = t >> 6;
  const int q0 = blockIdx.x * 128;
  const int bh = blockIdx.y;
  const int b = bh >> 3, h = bh & 7;
  const size_t abase = (size_t)bh * 1024 * 1024;
  const f16x8* VP8 = (const f16x8*)VP;
  f32x4 acc[2][4] = {};
  for (int j0 = 0; j0 < 1024; j0 += 64) {
    __syncthreads();
    #pragma unroll
    for (int rep = 0; rep < 8; ++rep) {
      int idx = rep * 1024 + t * 4;
      int q = idx >> 6, j = idx & 63;
      float4 v = *(const float4*)&attn[abase + (size_t)(q0 + q) * 1024 + j0 + j];
      *(f16x4*)&at[q][j] = f16x4{(f16)v.x, (f16)v.y, (f16)v.z, (f16)v.w};
    }
    __syncthreads();
    #pragma unroll
    for (int kc = 0; kc < 2; ++kc) {
      f16x8 pa[2];
      #pragma unroll
      for (int mb = 0; mb < 2; ++mb) {
        int row = w * 32 + mb * 16 + (l & 15);
        int jj = kc * 32 + (l >> 4) * 8;
        pa[mb] = *(const f16x8*)&at[row][jj];
      }
      #pragma unroll
      for (int nb = 0; nb < 4; ++nb) {
        f16x8 vb = VP8[(((size_t)bh * 4 + nb) * 32 + (j0 >> 5) + kc) * 64 + l];
        #pragma unroll
        for (int mb = 0; mb < 2; ++mb)
          acc[mb][nb] = MFMA16(pa[mb], vb, acc[mb][nb]);
      }
    }
  }
  #pragma unroll
  for (int mb = 0; mb < 2; ++mb)
  #pragma unroll
  for (int nb = 0; nb < 4; ++nb)
  #pragma unroll
  for (int r = 0; r < 4; ++r) {
    const int qg = q0 + w * 32 + mb * 16 + (l >> 4) * 4 + r;
    const int dd = nb * 16 + (l & 15);
    OUT1[((size_t)b * 1024 + qg) * 512 + h * 64 + dd] = (f16)acc[mb][nb][r];
  }
}

// ---------------- Kernel D: out = OUT1 @ w_out + b_out ----------------
__global__ __launch_bounds__(256) void kout(
    const f16* __restrict__ OUT1, const float* __restrict__ w_out,
    const float* __restrict__ b_out, float* __restrict__ out)
{
  __shared__ f16 a_s[128][36];
  __shared__ f16 b_s[64][36];
  const int t = threadIdx.x, l = t & 63, w = t >> 6;
  const int m0 = blockIdx.x * 128;
  const int c0 = blockIdx.y * 64;
  f32x4 acc[2][4] = {};
  for (int k0 = 0; k0 < 512; k0 += 32) {
    __syncthreads();
    #pragma unroll
    for (int rep = 0; rep < 2; ++rep) {
      int idx = rep * 2048 + t * 8;
      int r = idx >> 5, c = idx & 31;
      f16x8 v = *(const f16x8*)&OUT1[(size_t)(m0 + r) * 512 + k0 + c];
      *(f16x4*)&a_s[r][c]     = f16x4{v[0], v[1], v[2], v[3]};
      *(f16x4*)&a_s[r][c + 4] = f16x4{v[4], v[5], v[6], v[7]};
    }
    #pragma unroll
    for (int rep = 0; rep < 2; ++rep) {
      int idx = rep * 1024 + t * 4;
      int kr = idx >> 6, c = idx & 63;
      float4 v = *(const float4*)&w_out[(size_t)(k0 + kr) * 512 + c0 + c];
      b_s[c + 0][kr] = (f16)v.x; b_s[c + 1][kr] = (f16)v.y;
      b_s[c + 2][kr] = (f16)v.z; b_s[c + 3][kr] = (f16)v.w;
    }
    __syncthreads();
    const int kc = (l >> 4) * 8;
    f16x8 af[2];
    #pragma unroll
    for (int mb = 0; mb < 2; ++mb) {
      int r = w * 32 + mb * 16 + (l & 15);
      af[mb] = __builtin_shufflevector(*(const f16x4*)&a_s[r][kc], *(const f16x4*)&a_s[r][kc + 4],
                                       0, 1, 2, 3, 4, 5, 6, 7);
    }
    #pragma unroll
    for (int nb = 0; nb < 4; ++nb) {
      int cc = nb * 16 + (l & 15);
      f16x8 bf = __builtin_shufflevector(*(const f16x4*)&b_s[cc][kc], *(const f16x4*)&b_s[cc][kc + 4],
                                         0, 1, 2, 3, 4, 5, 6, 7);
      #pragma unroll
      for (int mb = 0; mb < 2; ++mb)
        acc[mb][nb] = MFMA16(af[mb], bf, acc[mb][nb]);
    }
  }
  #pragma unroll
  for (int mb = 0; mb < 2; ++mb)
  #pragma unroll
  for (int nb = 0; nb < 4; ++nb) {
    const int cg = c0 + nb * 16 + (l & 15);
    const float bb = b_out[cg];
    #pragma unroll
    for (int r = 0; r < 4; ++r) {
      const int m = m0 + w * 32 + mb * 16 + (l >> 4) * 4 + r;
      out[(size_t)m * 512 + cg] = acc[mb][nb][r] + bb;
    }
  }
}

extern "C" void kernel_launch(void* const* d_in, const int* in_sizes, int n_in,
                              void* d_out, int out_size, void* d_ws, size_t ws_size,
                              hipStream_t stream) {
  const float* x       = (const float*)d_in[0];
  const float* rt      = (const float*)d_in[1];
  const float* rc      = (const float*)d_in[2];
  const float* bias_te = (const float*)d_in[3];
  const float* w_qkv   = (const float*)d_in[7];
  const float* w_kr_t  = (const float*)d_in[8];
  const float* w_kr_c  = (const float*)d_in[9];
  const float* w_out   = (const float*)d_in[10];
  const float* b_out   = (const float*)d_in[11];
  float* out = (float*)d_out;
  float* attn_out = out + (size_t)8 * 1024 * 512;

  // f16 offsets
  const size_t oX16 = 0;
  const size_t oA2  = oX16 + 4194304;
  const size_t oWQ  = oA2  + 8388608;
  const size_t oW2  = oWQ  + 786432;
  const size_t oQP  = oW2  + 524288;
  const size_t oKP  = oQP  + 4194304;
  const size_t oVP  = oKP  + 4194304;
  const size_t oWP  = oVP  + 4194304;
  const size_t oO1  = oWP  + 4194304;
  const size_t oBD  = oO1  + 4194304;
  const size_t NEEDED = (oBD + 67108864) * 2;
  if (ws_size < NEEDED) return;
  f16* ws = (f16*)d_ws;
  f16 *X16 = ws + oX16, *A2 = ws + oA2, *WQ = ws + oWQ, *W2 = ws + oW2;
  f16 *QP = ws + oQP, *KP = ws + oKP, *VP = ws + oVP, *WP = ws + oWP;
  f16 *OUT1 = ws + oO1, *BD = ws + oBD;

  kprep<<<dim3(2048, 6), 256, 0, stream>>>(x, rt, rc, w_qkv, w_kr_t, w_kr_c,
                                           X16, A2, WQ, W2);
  kproj<<<dim3(64, 16), 256, 0, stream>>>(X16, A2, WQ, W2, bias_te, QP, KP, VP, WP);
  krel<<<dim3(8, 8, 64), 256, 0, stream>>>(QP, WP, BD);
  kdots<<<dim3(16, 32, 8), 512, 0, stream>>>(QP, KP, BD, attn_out);
  kpv<<<dim3(8, 64), 256, 0, stream>>>(attn_out, VP, OUT1);
  kout<<<dim3(64, 8), 256, 0, stream>>>(OUT1, w_out, b_out, out);
}

// Round 5
// 257.133 us; speedup vs baseline: 1.7818x; 1.2883x over previous
//
#include <hip/hip_runtime.h>
#include <hip/hip_fp16.h>

// B=8, N=1024, E=512, H=8, D=64
// ws (f16): X16[8192][512], A2[8192][1024], WQ[1536][512], W2[512][1024],
//           QP/KP/WP packed A/B-frag [64bh][64ft][2kc][64lane][8], VP packed,
//           OUT1[8192][512]   (BD eliminated: rel-shift fused into kdots)

typedef _Float16 f16;
typedef f16 f16x4 __attribute__((ext_vector_type(4)));
typedef f16 f16x8 __attribute__((ext_vector_type(8)));
typedef float f32x4 __attribute__((ext_vector_type(4)));

#define MFMA16(a,b,c) __builtin_amdgcn_mfma_f32_16x16x32_f16((a),(b),(c),0,0,0)

static __device__ __forceinline__ size_t qpidx(int bh, int q, int d) {
  return ((((size_t)bh * 64 + (q >> 4)) * 2 + (d >> 5)) * 64 +
          ((q & 15) + (((d >> 3) & 3) << 4))) * 8 + (d & 7);
}
static __device__ __forceinline__ size_t vpidx(int bh, int d, int j) {
  return ((((size_t)bh * 4 + (d >> 4)) * 32 + (j >> 5)) * 64 +
          ((d & 15) + (((j >> 3) & 3) << 4))) * 8 + (j & 7);
}

// ---------------- Kernel 0: prep (convert + concat + transpose weights) -----
__global__ __launch_bounds__(256) void kprep(
    const float* __restrict__ x, const float* __restrict__ rt, const float* __restrict__ rc,
    const float* __restrict__ wqkv, const float* __restrict__ wkrt, const float* __restrict__ wkrc,
    f16* __restrict__ X16, f16* __restrict__ A2, f16* __restrict__ WQ, f16* __restrict__ W2)
{
  const int t = threadIdx.x, gx = blockIdx.x, mode = blockIdx.y;
  if (mode <= 2) {
    const size_t id = (size_t)gx * 256 + t;
    const float* src = (mode == 0) ? x : (mode == 1) ? rt : rc;
    float4 v0 = *(const float4*)&src[id * 8];
    float4 v1 = *(const float4*)&src[id * 8 + 4];
    f16x8 o = {(f16)v0.x, (f16)v0.y, (f16)v0.z, (f16)v0.w,
               (f16)v1.x, (f16)v1.y, (f16)v1.z, (f16)v1.w};
    if (mode == 0) *(f16x8*)&X16[id * 8] = o;
    else {
      const int mrow = (int)(id >> 6), cc = (int)(id & 63);
      *(f16x8*)&A2[(size_t)mrow * 1024 + (mode == 2 ? 512 : 0) + cc * 8] = o;
    }
  } else if (mode == 3) {
    if (gx >= 384) return;
    const int c = gx & 63, n = (gx >> 6) * 256 + t;
    f16x8 o;
    #pragma unroll
    for (int e = 0; e < 8; ++e) o[e] = (f16)wqkv[(size_t)(c * 8 + e) * 1536 + n];
    *(f16x8*)&WQ[(size_t)n * 512 + c * 8] = o;
  } else {
    if (gx >= 128) return;
    const int c = gx & 63, n = (gx >> 6) * 256 + t;
    const float* src = (mode == 4) ? wkrt : wkrc;
    f16x8 o;
    #pragma unroll
    for (int e = 0; e < 8; ++e) o[e] = (f16)src[(size_t)(c * 8 + e) * 512 + n];
    *(f16x8*)&W2[(size_t)n * 1024 + (mode == 5 ? 512 : 0) + c * 8] = o;
  }
}

// ---------------- Kernel A: projections (128x128 tile, BK=64, swizzled LDS) --
__global__ __launch_bounds__(256) void kproj(
    const f16* __restrict__ X16, const f16* __restrict__ A2,
    const f16* __restrict__ WQ, const f16* __restrict__ W2,
    const float* __restrict__ bias_te,
    f16* __restrict__ QP, f16* __restrict__ KP, f16* __restrict__ VP, f16* __restrict__ WP)
{
  __shared__ f16 As[128 * 64];
  __shared__ f16 Bs[128 * 64];
  const int t = threadIdx.x, l = t & 63, w = t >> 6;
  const int wr = w >> 1, wc = w & 1;
  const int m0 = blockIdx.x * 128;
  const int y = blockIdx.y;
  const int mode = y >> 2;
  const bool wrs = (mode == 3);
  const f16* Asrc = wrs ? A2 : X16;
  const int lda = wrs ? 1024 : 512;
  const int K = wrs ? 1024 : 512;
  const f16* Bsrc = wrs ? (W2 + (size_t)((y - 12) * 128) * 1024)
                        : (WQ + (size_t)(y * 128) * 512);
  const int ldb = wrs ? 1024 : 512;

  f32x4 acc[4][4] = {};
  for (int k0 = 0; k0 < K; k0 += 64) {
    __syncthreads();
    #pragma unroll
    for (int rep = 0; rep < 4; ++rep) {
      const int idx = rep * 256 + t;
      const int row = idx >> 3, kb = idx & 7;
      const int slot = (kb ^ (row & 7)) << 3;
      f16x8 va = *(const f16x8*)&Asrc[(size_t)(m0 + row) * lda + k0 + kb * 8];
      *(f16x8*)&As[row * 64 + slot] = va;
      f16x8 vb = *(const f16x8*)&Bsrc[(size_t)row * ldb + k0 + kb * 8];
      *(f16x8*)&Bs[row * 64 + slot] = vb;
    }
    __syncthreads();
    #pragma unroll
    for (int kc = 0; kc < 2; ++kc) {
      f16x8 af[4], bf[4];
      const int kb = kc * 4 + (l >> 4);
      #pragma unroll
      for (int mb = 0; mb < 4; ++mb) {
        const int r = wr * 64 + mb * 16 + (l & 15);
        af[mb] = *(const f16x8*)&As[r * 64 + ((kb ^ (r & 7)) << 3)];
      }
      #pragma unroll
      for (int nb = 0; nb < 4; ++nb) {
        const int r = wc * 64 + nb * 16 + (l & 15);
        bf[nb] = *(const f16x8*)&Bs[r * 64 + ((kb ^ (r & 7)) << 3)];
      }
      #pragma unroll
      for (int mb = 0; mb < 4; ++mb)
      #pragma unroll
      for (int nb = 0; nb < 4; ++nb)
        acc[mb][nb] = MFMA16(af[mb], bf[nb], acc[mb][nb]);
    }
  }
  #pragma unroll
  for (int mb = 0; mb < 4; ++mb)
  #pragma unroll
  for (int nb = 0; nb < 4; ++nb) {
    const int loc = wc * 64 + nb * 16 + (l & 15);
    const int c = (y & 3) * 128 + loc;
    const int hh = c >> 6, d = c & 63;
    const float badd = (mode == 0) ? bias_te[c] : 0.f;
    f32x4 a = acc[mb][nb];
    #pragma unroll
    for (int r = 0; r < 4; ++r) {
      const int m = m0 + wr * 64 + mb * 16 + (l >> 4) * 4 + r;
      const int bb = m >> 10, tn = m & 1023;
      const int bh = bb * 8 + hh;
      const float v = a[r] + badd;
      if (mode == 0)      QP[qpidx(bh, tn, d)] = (f16)v;
      else if (mode == 1) KP[qpidx(bh, tn, d)] = (f16)v;
      else if (mode == 2) VP[vpidx(bh, d, tn)] = (f16)v;
      else                WP[qpidx(bh, tn, d)] = (f16)v;
    }
  }
}

// ---------------- Kernel C1: fused rel-shift + dots + h-softmax + attn -------
// grid (ktile 16, qtile 32, b 8); 512 threads, wave = head.
// Shift map (verified vs passing krel): raw[a,jj] ->
//   region A (a+jj>=1023): dest (q=a,   k=a+jj-1023)   [k<=q]
//   region B (a+jj< 1023): dest (q=a-1, k=a+jj+1)      [k>=q+2]
// Hole at k=q+1 stays zero. Tile rows q0..q0+31 need raw rows q0..q0+32
// -> compute 3 16-row fragments (q0..q0+47); extra rows provably never stored.
__global__ __launch_bounds__(512) void kdots(
    const f16* __restrict__ QP, const f16* __restrict__ KP,
    const f16* __restrict__ WP, float* __restrict__ attn_out)
{
  __shared__ f16 sd[8][32][72];
  const int t = threadIdx.x, l = t & 63, h = t >> 6;
  const int k0 = blockIdx.x * 64;
  const int q0 = blockIdx.y * 32;
  const int b = blockIdx.z;
  const int bh = b * 8 + h;
  const f16x8* QP8 = (const f16x8*)QP;
  const f16x8* KP8 = (const f16x8*)KP;
  const f16x8* WP8 = (const f16x8*)WP;
  // Q fragments: rows q0..q0+47 (3rd only feeds region B's row q0+32)
  f16x8 aq[3][2];
  #pragma unroll
  for (int mb = 0; mb < 3; ++mb)
  #pragma unroll
  for (int kc = 0; kc < 2; ++kc)
    aq[mb][kc] = QP8[((size_t)(bh * 64 + (q0 >> 4) + mb) * 2 + kc) * 64 + l];
  // zero the dots tile
  {
    f16* sdf = (f16*)sd;
    for (int i = t; i < 2304; i += 512) *(f16x8*)&sdf[(size_t)i * 8] = f16x8{};
  }
  __syncthreads();
  // ---- raw (qb . WRS^T) for the two j-windows, scatter 0.5*raw into sd ----
  const int u0 = k0 - q0;
  const int qrow = (l >> 4) * 4;
  auto rawblock = [&](int jb) {
    f32x4 racc[3] = {};
    #pragma unroll
    for (int kc = 0; kc < 2; ++kc) {
      f16x8 bf = WP8[((size_t)(bh * 64 + jb) * 2 + kc) * 64 + l];
      #pragma unroll
      for (int mb = 0; mb < 3; ++mb)
        racc[mb] = MFMA16(aq[mb][kc], bf, racc[mb]);
    }
    const int jglob = jb * 16 + (l & 15);
    #pragma unroll
    for (int mb = 0; mb < 3; ++mb)
    #pragma unroll
    for (int r = 0; r < 4; ++r) {
      const int qloc = mb * 16 + qrow + r;     // raw row a = q0 + qloc
      const int a = q0 + qloc;
      const f16 v = (f16)(0.5f * racc[mb][r]);
      if (qloc < 32) {                          // region A: dest (a, a+jj-1023)
        const int kA = a + jglob - 1023;
        if (kA >= k0 && kA < k0 + 64) sd[h][qloc][kA - k0] = v;
      }
      if (qloc >= 1 && qloc <= 32) {            // region B: dest (a-1, a+jj+1)
        const int kB = a + jglob + 1;
        if (kB >= k0 && kB < k0 + 64) sd[h][qloc - 1][kB - k0] = v;
      }
    }
  };
  {
    // region B jj-window: [u0-33, u0+61]
    const int blo_e = u0 - 33, bhi_e = (u0 + 61 > 1023) ? 1023 : u0 + 61;
    if (bhi_e >= 0) {
      const int blo = (blo_e < 0 ? 0 : blo_e) >> 4, bhi = bhi_e >> 4;
      for (int jb = blo; jb <= bhi; ++jb) rawblock(jb);
    }
    // region A jj-window: [u0+992, u0+1086] (exists iff u0<=31)
    if (u0 <= 31) {
      const int alo_e = 992 + u0, ahi_e = (1086 + u0 > 1023) ? 1023 : 1086 + u0;
      const int alo = (alo_e < 0 ? 0 : alo_e) >> 4, ahi = ahi_e >> 4;
      for (int jb = alo; jb <= ahi; ++jb) rawblock(jb);
    }
  }
  __syncthreads();
  // ---- AC = QB . K^T, add into sd ----
  f32x4 acc[2][4] = {};
  #pragma unroll
  for (int kc = 0; kc < 2; ++kc) {
    #pragma unroll
    for (int nb = 0; nb < 4; ++nb) {
      f16x8 bf = KP8[((size_t)(bh * 64 + (k0 >> 4) + nb) * 2 + kc) * 64 + l];
      #pragma unroll
      for (int mb = 0; mb < 2; ++mb)
        acc[mb][nb] = MFMA16(aq[mb][kc], bf, acc[mb][nb]);
    }
  }
  #pragma unroll
  for (int mb = 0; mb < 2; ++mb)
  #pragma unroll
  for (int nb = 0; nb < 4; ++nb)
  #pragma unroll
  for (int r = 0; r < 4; ++r) {
    const int qloc = mb * 16 + qrow + r, kloc = nb * 16 + (l & 15);
    sd[h][qloc][kloc] = (f16)((float)sd[h][qloc][kloc] + acc[mb][nb][r]);
  }
  __syncthreads();
  // ---- softmax over heads + attn write ----
  {
    const int o = t * 4, q = o >> 6, k = o & 63;
    float dv[8][4];
    #pragma unroll
    for (int hh = 0; hh < 8; ++hh) {
      f16x4 v = *(const f16x4*)&sd[hh][q][k];
      dv[hh][0] = (float)v[0]; dv[hh][1] = (float)v[1];
      dv[hh][2] = (float)v[2]; dv[hh][3] = (float)v[3];
    }
    #pragma unroll
    for (int e = 0; e < 4; ++e) {
      float m = dv[0][e];
      #pragma unroll
      for (int hh = 1; hh < 8; ++hh) m = fmaxf(m, dv[hh][e]);
      float ssum = 0.f;
      #pragma unroll
      for (int hh = 0; hh < 8; ++hh) { float a = __expf(dv[hh][e] - m); dv[hh][e] = a; ssum += a; }
      float rinv = 1.f / ssum;
      #pragma unroll
      for (int hh = 0; hh < 8; ++hh) dv[hh][e] *= rinv;
    }
    const size_t qg = q0 + q;
    #pragma unroll
    for (int hh = 0; hh < 8; ++hh)
      *(float4*)&attn_out[((size_t)(b * 8 + hh) * 1024 + qg) * 1024 + k0 + k] =
          float4{dv[hh][0], dv[hh][1], dv[hh][2], dv[hh][3]};
  }
}

// ---------------- Kernel C2: PV = attn @ V -> OUT1 ----------------
__global__ __launch_bounds__(256) void kpv(
    const float* __restrict__ attn, const f16* __restrict__ VP, f16* __restrict__ OUT1)
{
  __shared__ f16 at[128][72];
  const int t = threadIdx.x, l = t & 63, w = t >> 6;
  const int q0 = blockIdx.x * 128;
  const int bh = blockIdx.y;
  const int b = bh >> 3, h = bh & 7;
  const size_t abase = (size_t)bh * 1024 * 1024;
  const f16x8* VP8 = (const f16x8*)VP;
  f32x4 acc[2][4] = {};
  for (int j0 = 0; j0 < 1024; j0 += 64) {
    __syncthreads();
    #pragma unroll
    for (int rep = 0; rep < 8; ++rep) {
      int idx = rep * 1024 + t * 4;
      int q = idx >> 6, j = idx & 63;
      float4 v = *(const float4*)&attn[abase + (size_t)(q0 + q) * 1024 + j0 + j];
      *(f16x4*)&at[q][j] = f16x4{(f16)v.x, (f16)v.y, (f16)v.z, (f16)v.w};
    }
    __syncthreads();
    #pragma unroll
    for (int kc = 0; kc < 2; ++kc) {
      f16x8 pa[2];
      #pragma unroll
      for (int mb = 0; mb < 2; ++mb) {
        int row = w * 32 + mb * 16 + (l & 15);
        int jj = kc * 32 + (l >> 4) * 8;
        pa[mb] = *(const f16x8*)&at[row][jj];
      }
      #pragma unroll
      for (int nb = 0; nb < 4; ++nb) {
        f16x8 vb = VP8[(((size_t)bh * 4 + nb) * 32 + (j0 >> 5) + kc) * 64 + l];
        #pragma unroll
        for (int mb = 0; mb < 2; ++mb)
          acc[mb][nb] = MFMA16(pa[mb], vb, acc[mb][nb]);
      }
    }
  }
  #pragma unroll
  for (int mb = 0; mb < 2; ++mb)
  #pragma unroll
  for (int nb = 0; nb < 4; ++nb)
  #pragma unroll
  for (int r = 0; r < 4; ++r) {
    const int qg = q0 + w * 32 + mb * 16 + (l >> 4) * 4 + r;
    const int dd = nb * 16 + (l & 15);
    OUT1[((size_t)b * 1024 + qg) * 512 + h * 64 + dd] = (f16)acc[mb][nb][r];
  }
}

// ---------------- Kernel D: out = OUT1 @ w_out + b_out ----------------
__global__ __launch_bounds__(256) void kout(
    const f16* __restrict__ OUT1, const float* __restrict__ w_out,
    const float* __restrict__ b_out, float* __restrict__ out)
{
  __shared__ f16 a_s[128][36];
  __shared__ f16 b_s[64][36];
  const int t = threadIdx.x, l = t & 63, w = t >> 6;
  const int m0 = blockIdx.x * 128;
  const int c0 = blockIdx.y * 64;
  f32x4 acc[2][4] = {};
  for (int k0 = 0; k0 < 512; k0 += 32) {
    __syncthreads();
    #pragma unroll
    for (int rep = 0; rep < 2; ++rep) {
      int idx = rep * 2048 + t * 8;
      int r = idx >> 5, c = idx & 31;
      f16x8 v = *(const f16x8*)&OUT1[(size_t)(m0 + r) * 512 + k0 + c];
      *(f16x4*)&a_s[r][c]     = f16x4{v[0], v[1], v[2], v[3]};
      *(f16x4*)&a_s[r][c + 4] = f16x4{v[4], v[5], v[6], v[7]};
    }
    #pragma unroll
    for (int rep = 0; rep < 2; ++rep) {
      int idx = rep * 1024 + t * 4;
      int kr = idx >> 6, c = idx & 63;
      float4 v = *(const float4*)&w_out[(size_t)(k0 + kr) * 512 + c0 + c];
      b_s[c + 0][kr] = (f16)v.x; b_s[c + 1][kr] = (f16)v.y;
      b_s[c + 2][kr] = (f16)v.z; b_s[c + 3][kr] = (f16)v.w;
    }
    __syncthreads();
    const int kc = (l >> 4) * 8;
    f16x8 af[2];
    #pragma unroll
    for (int mb = 0; mb < 2; ++mb) {
      int r = w * 32 + mb * 16 + (l & 15);
      af[mb] = __builtin_shufflevector(*(const f16x4*)&a_s[r][kc], *(const f16x4*)&a_s[r][kc + 4],
                                       0, 1, 2, 3, 4, 5, 6, 7);
    }
    #pragma unroll
    for (int nb = 0; nb < 4; ++nb) {
      int cc = nb * 16 + (l & 15);
      f16x8 bf = __builtin_shufflevector(*(const f16x4*)&b_s[cc][kc], *(const f16x4*)&b_s[cc][kc + 4],
                                         0, 1, 2, 3, 4, 5, 6, 7);
      #pragma unroll
      for (int mb = 0; mb < 2; ++mb)
        acc[mb][nb] = MFMA16(af[mb], bf, acc[mb][nb]);
    }
  }
  #pragma unroll
  for (int mb = 0; mb < 2; ++mb)
  #pragma unroll
  for (int nb = 0; nb < 4; ++nb) {
    const int cg = c0 + nb * 16 + (l & 15);
    const float bb = b_out[cg];
    #pragma unroll
    for (int r = 0; r < 4; ++r) {
      const int m = m0 + w * 32 + mb * 16 + (l >> 4) * 4 + r;
      out[(size_t)m * 512 + cg] = acc[mb][nb][r] + bb;
    }
  }
}

extern "C" void kernel_launch(void* const* d_in, const int* in_sizes, int n_in,
                              void* d_out, int out_size, void* d_ws, size_t ws_size,
                              hipStream_t stream) {
  const float* x       = (const float*)d_in[0];
  const float* rt      = (const float*)d_in[1];
  const float* rc      = (const float*)d_in[2];
  const float* bias_te = (const float*)d_in[3];
  const float* w_qkv   = (const float*)d_in[7];
  const float* w_kr_t  = (const float*)d_in[8];
  const float* w_kr_c  = (const float*)d_in[9];
  const float* w_out   = (const float*)d_in[10];
  const float* b_out   = (const float*)d_in[11];
  float* out = (float*)d_out;
  float* attn_out = out + (size_t)8 * 1024 * 512;

  const size_t oX16 = 0;
  const size_t oA2  = oX16 + 4194304;
  const size_t oWQ  = oA2  + 8388608;
  const size_t oW2  = oWQ  + 786432;
  const size_t oQP  = oW2  + 524288;
  const size_t oKP  = oQP  + 4194304;
  const size_t oVP  = oKP  + 4194304;
  const size_t oWP  = oVP  + 4194304;
  const size_t oO1  = oWP  + 4194304;
  const size_t NEEDED = (oO1 + 4194304) * 2;
  if (ws_size < NEEDED) return;
  f16* ws = (f16*)d_ws;
  f16 *X16 = ws + oX16, *A2 = ws + oA2, *WQ = ws + oWQ, *W2 = ws + oW2;
  f16 *QP = ws + oQP, *KP = ws + oKP, *VP = ws + oVP, *WP = ws + oWP;
  f16 *OUT1 = ws + oO1;

  kprep<<<dim3(2048, 6), 256, 0, stream>>>(x, rt, rc, w_qkv, w_kr_t, w_kr_c,
                                           X16, A2, WQ, W2);
  kproj<<<dim3(64, 16), 256, 0, stream>>>(X16, A2, WQ, W2, bias_te, QP, KP, VP, WP);
  kdots<<<dim3(16, 32, 8), 512, 0, stream>>>(QP, KP, WP, attn_out);
  kpv<<<dim3(8, 64), 256, 0, stream>>>(attn_out, VP, OUT1);
  kout<<<dim3(64, 8), 256, 0, stream>>>(OUT1, w_out, b_out, out);
}